// Round 3
// baseline (1218.639 us; speedup 1.0000x reference)
//
#include <hip/hip_runtime.h>
#include <math.h>

namespace {

constexpr int B  = 16;
constexpr int S  = 1024;
constexpr int H  = 768;
constexpr int NH = 12;
constexpr int DH = 64;
constexpr int FF = 3072;
constexpr int XSPL = 32;
constexpr int NBLK = 512;      // 2 blocks/CU x 256 CUs, co-resident by launch_bounds(256,2)
constexpr float EPS = 1e-12f;

// global-barrier state: zero-initialized at module load; gen is monotonic so
// repeated graph replays are safe; cnt returns to 0 after every barrier.
__device__ __attribute__((aligned(128))) unsigned g_cnt = 0;
__device__ __attribute__((aligned(128))) unsigned g_gen = 0;

struct Params {
    const float *x, *mask, *wq, *bq, *wk, *bk, *wv, *bv, *wo, *bo;
    const float *ln1g, *ln1b, *w1, *b1, *w2, *b2, *ln2g, *ln2b, *wp, *bp, *wm, *bm;
    float *out;
    float *u, *constk, *psum, *attn_out, *hidden;
    float *xpart, *ctx_part, *wo_part, *ffn1_part, *ffn2_part, *pool_part;
};

// device-scope sense-reversal grid barrier (all NBLK blocks must be resident).
// Failsafe spin cap: terminates (wrong answer) instead of hanging if residency
// assumptions are ever violated.
__device__ __forceinline__ void gbar() {
    __syncthreads();
    __threadfence();   // release: drain this block's global writes device-wide
    if (threadIdx.x == 0) {
        const unsigned g = __hip_atomic_load(&g_gen, __ATOMIC_RELAXED, __HIP_MEMORY_SCOPE_AGENT);
        const unsigned a = __hip_atomic_fetch_add(&g_cnt, 1u, __ATOMIC_ACQ_REL, __HIP_MEMORY_SCOPE_AGENT);
        if (a == NBLK - 1) {
            __hip_atomic_store(&g_cnt, 0u, __ATOMIC_RELAXED, __HIP_MEMORY_SCOPE_AGENT);
            __hip_atomic_fetch_add(&g_gen, 1u, __ATOMIC_RELEASE, __HIP_MEMORY_SCOPE_AGENT);
        } else {
            int t = 0;
            while (__hip_atomic_load(&g_gen, __ATOMIC_ACQUIRE, __HIP_MEMORY_SCOPE_AGENT) == g) {
                __builtin_amdgcn_s_sleep(4);
                if (++t > (1 << 18)) break;   // ~28 ms failsafe
            }
        }
    }
    __syncthreads();
    __threadfence();   // acquire side for all waves (L1 invalidate)
}

__device__ __forceinline__ float waveReduceSum(float v) {
#pragma unroll
    for (int d = 1; d < 64; d <<= 1) v += __shfl_xor(v, d);
    return v;
}

// 256-thread block reduce (4 waves); leading syncthreads protects smem reuse
__device__ __forceinline__ float blockReduceSum256(float v, float* red) {
    const int tid = threadIdx.x;
    v = waveReduceSum(v);
    __syncthreads();
    if ((tid & 63) == 0) red[tid >> 6] = v;
    __syncthreads();
    return red[0] + red[1] + red[2] + red[3];
}

// inner tile GEMM: 64 j-lanes x 4 b-groups, A staged in Asl[B][IR]
template <int IR, int N>
__device__ __forceinline__ void gemmInner(const float* Asl, const float* __restrict__ W,
        float* __restrict__ part, int i0, int jt, int sp, int tid) {
    const int jl = tid & 63;
    const int bg = tid >> 6;
    const int j  = jt * 64 + jl;
    const float* wp_ = W + (size_t)i0 * N + j;
    const float* a0 = Asl + (bg * 4 + 0) * IR;
    const float* a1 = Asl + (bg * 4 + 1) * IR;
    const float* a2 = Asl + (bg * 4 + 2) * IR;
    const float* a3 = Asl + (bg * 4 + 3) * IR;
    float acc0 = 0.f, acc1 = 0.f, acc2 = 0.f, acc3 = 0.f;
#pragma unroll
    for (int ii = 0; ii < IR; ++ii) {
        const float w = wp_[(size_t)ii * N];
        acc0 += w * a0[ii];
        acc1 += w * a1[ii];
        acc2 += w * a2[ii];
        acc3 += w * a3[ii];
    }
    float* pp = part + ((size_t)sp * B) * N + j;
    pp[(size_t)(bg * 4 + 0) * N] = acc0;
    pp[(size_t)(bg * 4 + 1) * N] = acc1;
    pp[(size_t)(bg * 4 + 2) * N] = acc2;
    pp[(size_t)(bg * 4 + 3) * N] = acc3;
}

__global__ __launch_bounds__(256, 2) void bert_mega(Params p) {
    __shared__ __align__(16) float smem[9664];   // 38,656 B; 2 blocks/CU < 160 KB
    const int tid = threadIdx.x;
    const int bid = blockIdx.x;

    // ---------------- P1: q0 + u + constk (blocks 0..191) ----------------
    if (bid < B * NH) {
        const int b = bid / NH, h = bid % NH;
        float* qh  = smem;          // 64
        float* red = smem + 64;     // 4*64
        const int d = tid & 63, seg = tid >> 6;
        {
            const float* xr  = p.x + (size_t)b * S * H;               // row 0 of b
            const float* wqp = p.wq + (size_t)(seg * 192) * H + h * DH + d;
            float acc = 0.f;
#pragma unroll 8
            for (int i = 0; i < 192; ++i)
                acc += xr[seg * 192 + i] * wqp[(size_t)i * H];
            red[seg * 64 + d] = acc;
        }
        __syncthreads();
        if (tid < DH)
            qh[tid] = p.bq[h * DH + tid] + red[0 * 64 + tid] + red[1 * 64 + tid]
                                         + red[2 * 64 + tid] + red[3 * 64 + tid];
        __syncthreads();
        if (tid < DH) {
            float v = p.bk[h * DH + tid] * qh[tid];
            v = waveReduceSum(v);
            if (tid == 0) p.constk[b * NH + h] = v;
        }
        const int jj = tid & 3, iq = tid >> 2;
        const float4* qv = (const float4*)qh;
        float4 q4[4];
#pragma unroll
        for (int c = 0; c < 4; ++c) q4[c] = qv[jj * 4 + c];
#pragma unroll 4
        for (int ir = 0; ir < 12; ++ir) {
            const int i = ir * 64 + iq;
            const float4* wr = (const float4*)(p.wk + (size_t)i * H + h * DH);
            float s = 0.f;
#pragma unroll
            for (int c = 0; c < 4; ++c) {
                const float4 w = wr[jj * 4 + c];
                s += w.x * q4[c].x + w.y * q4[c].y + w.z * q4[c].z + w.w * q4[c].w;
            }
            s += __shfl_xor(s, 1);
            s += __shfl_xor(s, 2);
            if (jj == 0) p.u[((size_t)(b * NH + h)) * H + i] = s;
        }
    }
    gbar();

    // ---------------- P2: score + xbar partial (all 512 blocks) ----------------
    {
        const int b  = bid >> 5;
        const int kt = bid & 31;
        float* ul   = smem;             // 9216
        float* ck   = smem + 9216;      // 12
        float* wsum = smem + 9228;      // 4*12
        float* el   = smem + 9280;      // 32*12  (byte 37120, 16B aligned)
        {
            const float4* ug = (const float4*)(p.u + (size_t)b * NH * H);
            float4* ul4 = (float4*)ul;
            for (int e = tid; e < NH * H / 4; e += 256) ul4[e] = ug[e];
            if (tid < NH) ck[tid] = p.constk[b * NH + tid];
        }
        __syncthreads();

        const int jj = tid & 15, kk = tid >> 4;
        const int k0 = kt * 32 + kk * 2;
        float4 xv0[12], xv1[12];
        {
            const float4* xr0 = (const float4*)(p.x + ((size_t)b * S + k0) * H);
            const float4* xr1 = (const float4*)(p.x + ((size_t)b * S + k0 + 1) * H);
#pragma unroll
            for (int t = 0; t < 12; ++t) { xv0[t] = xr0[jj + 16 * t]; xv1[t] = xr1[jj + 16 * t]; }
        }
        const float4* ul4 = (const float4*)ul;
        float acc0[NH], acc1[NH];
#pragma unroll
        for (int h = 0; h < NH; ++h) {
            float a0 = 0.f, a1 = 0.f;
#pragma unroll
            for (int t = 0; t < 12; ++t) {
                const float4 uv = ul4[h * 192 + jj + 16 * t];
                a0 += xv0[t].x * uv.x + xv0[t].y * uv.y + xv0[t].z * uv.z + xv0[t].w * uv.w;
                a1 += xv1[t].x * uv.x + xv1[t].y * uv.y + xv1[t].z * uv.z + xv1[t].w * uv.w;
            }
            acc0[h] = a0; acc1[h] = a1;
        }
#pragma unroll
        for (int h = 0; h < NH; ++h) {
#pragma unroll
            for (int d = 1; d < 16; d <<= 1) {
                acc0[h] += __shfl_xor(acc0[h], d);
                acc1[h] += __shfl_xor(acc1[h], d);
            }
        }
        const float mk0 = p.mask[b * S + k0];
        const float mk1 = p.mask[b * S + k0 + 1];
        float e0[NH], e1[NH], ps[NH];
#pragma unroll
        for (int h = 0; h < NH; ++h) {
            e0[h] = expf(acc0[h] * 0.125f + ck[h] + mk0);
            e1[h] = expf(acc1[h] * 0.125f + ck[h] + mk1);
            ps[h] = e0[h] + e1[h];
        }
        if (jj == 0) {
#pragma unroll
            for (int h = 0; h < NH; ++h) {
                el[(kk * 2 + 0) * NH + h] = e0[h];
                el[(kk * 2 + 1) * NH + h] = e1[h];
            }
        }
#pragma unroll
        for (int h = 0; h < NH; ++h) {
            ps[h] += __shfl_xor(ps[h], 16);
            ps[h] += __shfl_xor(ps[h], 32);
        }
        const int wid = tid >> 6;
        if ((tid & 63) == 0) {
#pragma unroll
            for (int h = 0; h < NH; ++h) wsum[wid * NH + h] = ps[h];
        }
        __syncthreads();   // publishes el[][] AND wsum[][]
        if (tid < NH)
            p.psum[((size_t)(b * XSPL + kt)) * NH + tid] =
                wsum[0 * NH + tid] + wsum[1 * NH + tid] + wsum[2 * NH + tid] + wsum[3 * NH + tid];

        // phase 2: xbar partials; x rows L1/L2-hot; el rows read as 3x float4
        float accx[3][NH];
#pragma unroll
        for (int c = 0; c < 3; ++c)
#pragma unroll
            for (int h = 0; h < NH; ++h) accx[c][h] = 0.f;
        const float* xb = p.x + ((size_t)b * S + (size_t)kt * 32) * H;
#pragma unroll 4
        for (int k = 0; k < 32; ++k) {
            const float xs0 = xb[(size_t)k * H + tid];
            const float xs1 = xb[(size_t)k * H + tid + 256];
            const float xs2 = xb[(size_t)k * H + tid + 512];
            const float4 ea = *(const float4*)(el + k * NH + 0);
            const float4 eb = *(const float4*)(el + k * NH + 4);
            const float4 ec = *(const float4*)(el + k * NH + 8);
            const float eh[12] = {ea.x, ea.y, ea.z, ea.w,
                                  eb.x, eb.y, eb.z, eb.w,
                                  ec.x, ec.y, ec.z, ec.w};
#pragma unroll
            for (int h = 0; h < NH; ++h) {
                accx[0][h] += eh[h] * xs0;
                accx[1][h] += eh[h] * xs1;
                accx[2][h] += eh[h] * xs2;
            }
        }
        float* op = p.xpart + ((size_t)(b * XSPL + kt)) * NH * H + tid;
#pragma unroll
        for (int h = 0; h < NH; ++h) {
            op[(size_t)h * H +   0] = accx[0][h];
            op[(size_t)h * H + 256] = accx[1][h];
            op[(size_t)h * H + 512] = accx[2][h];
        }
    }
    gbar();

    // ---------------- P3: ctx partials (xbar reduce + rinv) @ wv, 288 tiles ----------------
    if (bid < 288) {
        constexpr int IR = H / 24;     // 32
        const int jt = bid % 12, sp = bid / 12;
        const int i0 = sp * IR;
        float* Asl   = smem;           // 512
        float* rinvl = smem + 512;     // 16
        if (tid < B) {
            float s = 0.f;
#pragma unroll
            for (int kt = 0; kt < XSPL; ++kt)
                s += p.psum[((size_t)(tid * XSPL + kt)) * NH + jt];
            rinvl[tid] = 1.0f / s;
        }
        __syncthreads();
        for (int e = tid; e < B * IR; e += 256) {
            const int bb = e / IR, ii = e % IR;
            float v = 0.f;
#pragma unroll
            for (int s2 = 0; s2 < XSPL; ++s2)
                v += p.xpart[(((size_t)(bb * XSPL + s2)) * NH + jt) * H + i0 + ii];
            Asl[e] = v * rinvl[bb];
        }
        __syncthreads();
        gemmInner<IR, H>(Asl, p.wv, p.ctx_part, i0, jt, sp, tid);
    }
    gbar();

    // ---------------- P4: wo GEMM (ctx reduce + bv), 288 tiles ----------------
    if (bid < 288) {
        constexpr int IR = H / 24;
        const int jt = bid % 12, sp = bid / 12;
        const int i0 = sp * IR;
        float* Asl = smem;
        for (int e = tid; e < B * IR; e += 256) {
            const int bb = e / IR, ii = e % IR;
            float v = p.bv[i0 + ii];
#pragma unroll
            for (int s2 = 0; s2 < 24; ++s2)
                v += p.ctx_part[((size_t)s2 * B + bb) * H + i0 + ii];
            Asl[e] = v;
        }
        __syncthreads();
        gemmInner<IR, H>(Asl, p.wo, p.wo_part, i0, jt, sp, tid);
    }
    gbar();

    // ---------------- P5: LN1 (blocks 0..15) ----------------
    if (bid < B) {
        const int b = bid;
        float* red = smem;
        float v[3], dd[3];
#pragma unroll
        for (int c = 0; c < 3; ++c) {
            const int j = tid + 256 * c;
            float t = p.bo[j] + p.x[(size_t)b * S * H + j];   // residual = x[b,0,:]
#pragma unroll
            for (int sp = 0; sp < 24; ++sp) t += p.wo_part[((size_t)sp * B + b) * H + j];
            v[c] = t;
        }
        const float mu = blockReduceSum256(v[0] + v[1] + v[2], red) * (1.0f / H);
        float q = 0.f;
#pragma unroll
        for (int c = 0; c < 3; ++c) { dd[c] = v[c] - mu; q += dd[c] * dd[c]; }
        const float var = blockReduceSum256(q, red) * (1.0f / H);
        const float r = rsqrtf(var + EPS);
#pragma unroll
        for (int c = 0; c < 3; ++c) {
            const int j = tid + 256 * c;
            p.attn_out[(size_t)b * H + j] = dd[c] * r * p.ln1g[j] + p.ln1b[j];
        }
    }
    gbar();

    // ---------------- P6: FFN1 (1152 tiles, <=3 per block) ----------------
    for (int t = bid; t < 48 * 24; t += NBLK) {
        constexpr int IR = H / 24;
        const int jt = t % 48, sp = t / 48;
        const int i0 = sp * IR;
        float* Asl = smem;
        __syncthreads();   // protect smem across tile iterations
        for (int e = tid; e < B * IR; e += 256) {
            const int bb = e / IR, ii = e % IR;
            Asl[e] = p.attn_out[(size_t)bb * H + i0 + ii];
        }
        __syncthreads();
        gemmInner<IR, FF>(Asl, p.w1, p.ffn1_part, i0, jt, sp, tid);
    }
    gbar();

    // ---------------- P7: FFN2 + GELU staging (576 tiles, <=2 per block) ----------------
    for (int t = bid; t < 12 * 48; t += NBLK) {
        constexpr int IR = FF / 48;    // 64
        const int jt = t % 12, sp = t / 12;
        const int i0 = sp * IR;
        float* Asl = smem;             // 1024
        __syncthreads();
        for (int e = tid; e < B * IR; e += 256) {
            const int bb = e / IR, ii = e % IR;
            float v = p.b1[i0 + ii];
#pragma unroll
            for (int s2 = 0; s2 < 24; ++s2)
                v += p.ffn1_part[((size_t)s2 * B + bb) * FF + i0 + ii];
            Asl[e] = 0.5f * v * (1.0f + erff(v * 0.70710678118654752440f));
        }
        __syncthreads();
        gemmInner<IR, H>(Asl, p.w2, p.ffn2_part, i0, jt, sp, tid);
    }
    gbar();

    // ---------------- P8: LN2 (blocks 0..15) ----------------
    if (bid < B) {
        const int b = bid;
        float* red = smem;
        float v[3], dd[3];
#pragma unroll
        for (int c = 0; c < 3; ++c) {
            const int j = tid + 256 * c;
            float t = p.b2[j] + p.attn_out[(size_t)b * H + j];   // residual = attn_out
#pragma unroll
            for (int sp = 0; sp < 48; ++sp) t += p.ffn2_part[((size_t)sp * B + b) * H + j];
            v[c] = t;
        }
        const float mu = blockReduceSum256(v[0] + v[1] + v[2], red) * (1.0f / H);
        float q = 0.f;
#pragma unroll
        for (int c = 0; c < 3; ++c) { dd[c] = v[c] - mu; q += dd[c] * dd[c]; }
        const float var = blockReduceSum256(q, red) * (1.0f / H);
        const float r = rsqrtf(var + EPS);
#pragma unroll
        for (int c = 0; c < 3; ++c) {
            const int j = tid + 256 * c;
            p.hidden[(size_t)b * H + j] = dd[c] * r * p.ln2g[j] + p.ln2b[j];
        }
    }
    gbar();

    // ---------------- P9: pooler GEMM (288 tiles) ----------------
    if (bid < 288) {
        constexpr int IR = H / 24;
        const int jt = bid % 12, sp = bid / 12;
        const int i0 = sp * IR;
        float* Asl = smem;
        for (int e = tid; e < B * IR; e += 256) {
            const int bb = e / IR, ii = e % IR;
            Asl[e] = p.hidden[(size_t)bb * H + i0 + ii];
        }
        __syncthreads();
        gemmInner<IR, H>(Asl, p.wp, p.pool_part, i0, jt, sp, tid);
    }
    gbar();

    // ---------------- P10: tanh-pool + classifier (blocks 0..15) ----------------
    if (bid < B) {
        const int b = bid;
        float* red = smem;
        float s = 0.f;
#pragma unroll
        for (int c = 0; c < 3; ++c) {
            const int j = tid + 256 * c;
            float v = p.bp[j];
#pragma unroll
            for (int sp = 0; sp < 24; ++sp) v += p.pool_part[((size_t)sp * B + b) * H + j];
            v = tanhf(v);
            s += v * p.wm[j];
        }
        s = blockReduceSum256(s, red);
        if (tid == 0) p.out[b] = s + p.bm[0];
    }
}

} // namespace

extern "C" void kernel_launch(void* const* d_in, const int* in_sizes, int n_in,
                              void* d_out, int out_size, void* d_ws, size_t ws_size,
                              hipStream_t stream) {
    Params p;
    p.x    = (const float*)d_in[0];
    p.mask = (const float*)d_in[1];
    p.wq   = (const float*)d_in[2];
    p.bq   = (const float*)d_in[3];
    p.wk   = (const float*)d_in[4];
    p.bk   = (const float*)d_in[5];
    p.wv   = (const float*)d_in[6];
    p.bv   = (const float*)d_in[7];
    p.wo   = (const float*)d_in[8];
    p.bo   = (const float*)d_in[9];
    p.ln1g = (const float*)d_in[10];
    p.ln1b = (const float*)d_in[11];
    p.w1   = (const float*)d_in[12];
    p.b1   = (const float*)d_in[13];
    p.w2   = (const float*)d_in[14];
    p.b2   = (const float*)d_in[15];
    p.ln2g = (const float*)d_in[16];
    p.ln2b = (const float*)d_in[17];
    p.wp   = (const float*)d_in[18];
    p.bp   = (const float*)d_in[19];
    p.wm   = (const float*)d_in[20];
    p.bm   = (const float*)d_in[21];
    p.out  = (float*)d_out;

    // -------- workspace (lifetime-overlapped arena; ~21.5 MB) --------
    float* ws = (float*)d_ws;
    size_t o = 0;
    p.u        = ws + o; o += (size_t)B * NH * H;      // 147456
    p.constk   = ws + o; o += 256;
    p.psum     = ws + o; o += (size_t)B * XSPL * NH;   // 6144
    p.attn_out = ws + o; o += (size_t)B * H;
    p.hidden   = ws + o; o += (size_t)B * H;
    float* arena = ws + o;
    // arena aliases (sequential lifetimes):
    p.xpart     = arena;                                  // XSPL*B*NH*H = 4718592
    p.ctx_part  = arena + (size_t)XSPL * B * NH * H;      // 24*B*H (reads xpart)
    p.wo_part   = p.ctx_part + (size_t)24 * B * H;        // 24*B*H (reads ctx_part)
    p.ffn1_part = arena;                                  // 24*B*FF (xpart dead)
    p.ffn2_part = arena + (size_t)24 * B * FF;            // 48*B*H (reads ffn1_part)
    p.pool_part = arena;                                  // 24*B*H (ffn1 dead)
    (void)ws_size; (void)in_sizes; (void)n_in; (void)out_size;

    hipLaunchKernelGGL(bert_mega, dim3(NBLK), dim3(256), 0, stream, p);
}

// Round 4
// 212.584 us; speedup vs baseline: 5.7325x; 5.7325x over previous
//
#include <hip/hip_runtime.h>
#include <math.h>

namespace {

constexpr int B  = 16;
constexpr int S  = 1024;
constexpr int H  = 768;
constexpr int NH = 12;
constexpr int DH = 64;
constexpr int FF = 3072;
constexpr int XSPL = 32;       // xbar k-splits (one per 32-key score tile)
constexpr float EPS = 1e-12f;

__device__ __forceinline__ float waveReduceSum(float v) {
#pragma unroll
    for (int d = 1; d < 64; d <<= 1) v += __shfl_xor(v, d);
    return v;
}

__device__ __forceinline__ float blockReduceSum768(float v, float* red) {
    const int lane = threadIdx.x & 63;
    const int wid  = threadIdx.x >> 6;
    v = waveReduceSum(v);
    __syncthreads();
    if (lane == 0) red[wid] = v;
    __syncthreads();
    float s = 0.f;
#pragma unroll
    for (int w = 0; w < 12; ++w) s += red[w];
    return s;
}

// ---------------------------------------------------------------------------
// split-K partial GEMM over the 16 CLS rows:
//   part[sp][b][j] = sum_{i in split sp} A[b,i] * W[i,j]
// grid (N/64, ISPL), block 256 = 64 j-lanes x 4 b-groups
// ---------------------------------------------------------------------------
template <int K, int ISPL, int N>
__global__ __launch_bounds__(256) void gemm_partial(
        const float* __restrict__ A, int lda, int jtOfsA,
        const float* __restrict__ W, float* __restrict__ part) {
    constexpr int IR = K / ISPL;
    __shared__ float Asl[B * IR];
    const int jt  = blockIdx.x;
    const int sp  = blockIdx.y;
    const int i0  = sp * IR;
    const int tid = threadIdx.x;

    for (int e = tid; e < B * IR; e += 256) {
        const int b = e / IR, ii = e % IR;
        Asl[e] = A[(size_t)b * lda + (size_t)jt * jtOfsA + i0 + ii];
    }
    __syncthreads();

    const int jl = tid & 63;
    const int bg = tid >> 6;
    const int j  = jt * 64 + jl;
    const float* wp_ = W + (size_t)i0 * N + j;
    const float* a0 = Asl + (bg * 4 + 0) * IR;
    const float* a1 = Asl + (bg * 4 + 1) * IR;
    const float* a2 = Asl + (bg * 4 + 2) * IR;
    const float* a3 = Asl + (bg * 4 + 3) * IR;
    float acc0 = 0.f, acc1 = 0.f, acc2 = 0.f, acc3 = 0.f;
#pragma unroll
    for (int ii = 0; ii < IR; ++ii) {
        const float w = wp_[(size_t)ii * N];
        acc0 += w * a0[ii];
        acc1 += w * a1[ii];
        acc2 += w * a2[ii];
        acc3 += w * a3[ii];
    }
    float* pp = part + ((size_t)sp * B) * N + j;
    pp[(size_t)(bg * 4 + 0) * N] = acc0;
    pp[(size_t)(bg * 4 + 1) * N] = acc1;
    pp[(size_t)(bg * 4 + 2) * N] = acc2;
    pp[(size_t)(bg * 4 + 3) * N] = acc3;
}

// out[b*K + i] = (bias + sum_sp part)  [optionally GELU]
// grid B*K/256, block 256
template <int K, int RED, bool GELU>
__global__ __launch_bounds__(256) void reduce_bias(
        const float* __restrict__ part, const float* __restrict__ bias,
        float* __restrict__ out) {
    const int e = blockIdx.x * 256 + threadIdx.x;
    const int b = e / K, i = e % K;
    float v = bias[i];
#pragma unroll 8
    for (int sp = 0; sp < RED; ++sp)
        v += part[((size_t)sp * B + b) * K + i];
    if (GELU) v = 0.5f * v * (1.0f + erff(v * 0.70710678118654752440f));
    out[e] = v;
}

// u[b,h,i] = sum_d wk[i, h*64+d] * q0r[b, h*64+d]; weights read exactly once.
// constk[b,h] = bk_h . q0r_h   (computed by the seg==0 block of each h)
// grid (NH, 12), block 256 = 64 i-lanes x 4 b-groups
__global__ __launch_bounds__(256) void u_kernel2(
        const float* __restrict__ q0r, const float* __restrict__ wk,
        const float* __restrict__ bk,
        float* __restrict__ u, float* __restrict__ constk) {
    const int h = blockIdx.x, seg = blockIdx.y;
    const int i0 = seg * 64;
    __shared__ float qh[B][DH + 1];     // +1 pad: spread banks
    __shared__ float wkl[64][DH + 1];   // +1 pad: avoid 32-way conflict
    const int tid = threadIdx.x;

    for (int e = tid; e < B * DH; e += 256) {
        const int b = e >> 6, d = e & 63;
        qh[b][d] = q0r[(size_t)b * H + h * DH + d];
    }
    {
        const float4* wg = (const float4*)(wk + (size_t)i0 * H + h * DH);
        for (int e = tid; e < 64 * 16; e += 256) {
            const int r = e >> 4, c4 = e & 15;
            const float4 w = wg[(size_t)r * (H / 4) + c4];
            wkl[r][c4 * 4 + 0] = w.x;
            wkl[r][c4 * 4 + 1] = w.y;
            wkl[r][c4 * 4 + 2] = w.z;
            wkl[r][c4 * 4 + 3] = w.w;
        }
    }
    __syncthreads();

    if (seg == 0 && tid < B) {
        float s = 0.f;
#pragma unroll
        for (int d = 0; d < DH; ++d) s += bk[h * DH + d] * qh[tid][d];
        constk[tid * NH + h] = s;
    }

    const int il = tid & 63;
    const int bg = tid >> 6;
    float acc0 = 0.f, acc1 = 0.f, acc2 = 0.f, acc3 = 0.f;
#pragma unroll
    for (int d = 0; d < DH; ++d) {
        const float w = wkl[il][d];
        acc0 += w * qh[bg * 4 + 0][d];
        acc1 += w * qh[bg * 4 + 1][d];
        acc2 += w * qh[bg * 4 + 2][d];
        acc3 += w * qh[bg * 4 + 3][d];
    }
    u[((size_t)((bg * 4 + 0) * NH + h)) * H + i0 + il] = acc0;
    u[((size_t)((bg * 4 + 1) * NH + h)) * H + i0 + il] = acc1;
    u[((size_t)((bg * 4 + 2) * NH + h)) * H + i0 + il] = acc2;
    u[((size_t)((bg * 4 + 3) * NH + h)) * H + i0 + il] = acc3;
}

// ctx partials with fused 32-way xbar-partial reduction AND softmax rinv:
//   A[b,i] = rinv[b,jt] * sum_s2 xpart[((b*32+s2)*NH + jt)*H + i]
template <int ISPL>
__global__ __launch_bounds__(256) void gemm_xpart(
        const float* __restrict__ xpart, const float* __restrict__ psum,
        const float* __restrict__ W, float* __restrict__ part) {
    constexpr int IR = H / ISPL;
    __shared__ float Asl[B * IR];
    __shared__ float rinvl[B];
    const int jt  = blockIdx.x;       // head
    const int sp  = blockIdx.y;
    const int i0  = sp * IR;
    const int tid = threadIdx.x;

    if (tid < B) {
        float s = 0.f;
#pragma unroll
        for (int kt = 0; kt < XSPL; ++kt)
            s += psum[((size_t)(tid * XSPL + kt)) * NH + jt];
        rinvl[tid] = 1.0f / s;
    }
    __syncthreads();

    for (int e = tid; e < B * IR; e += 256) {
        const int bb = e / IR, ii = e % IR;
        float v = 0.f;
#pragma unroll
        for (int s2 = 0; s2 < XSPL; ++s2)
            v += xpart[(((size_t)(bb * XSPL + s2)) * NH + jt) * H + i0 + ii];
        Asl[e] = v * rinvl[bb];
    }
    __syncthreads();

    const int jl = tid & 63;
    const int bg = tid >> 6;
    const int j  = jt * 64 + jl;
    const float* wp_ = W + (size_t)i0 * H + j;
    const float* a0 = Asl + (bg * 4 + 0) * IR;
    const float* a1 = Asl + (bg * 4 + 1) * IR;
    const float* a2 = Asl + (bg * 4 + 2) * IR;
    const float* a3 = Asl + (bg * 4 + 3) * IR;
    float acc0 = 0.f, acc1 = 0.f, acc2 = 0.f, acc3 = 0.f;
#pragma unroll
    for (int ii = 0; ii < IR; ++ii) {
        const float w = wp_[(size_t)ii * H];
        acc0 += w * a0[ii];
        acc1 += w * a1[ii];
        acc2 += w * a2[ii];
        acc3 += w * a3[ii];
    }
    float* pp = part + ((size_t)sp * B) * H + j;
    pp[(size_t)(bg * 4 + 0) * H] = acc0;
    pp[(size_t)(bg * 4 + 1) * H] = acc1;
    pp[(size_t)(bg * 4 + 2) * H] = acc2;
    pp[(size_t)(bg * 4 + 3) * H] = acc3;
}

// Fused score + xbar partial (verified in round 1):
//   e[k,h] = exp( x[b,k]·u[b,h]/8 + constk + mask )   (kept in LDS only)
//   psum[b][kt][h] = sum of e over this block's 32 k's
//   xpart[b][kt][h][j] = sum_{k in tile} e[k,h] * x[b,k,j]   (UN-normalized)
// grid (B, S/32), block 256
__global__ __launch_bounds__(256, 2) void score_xbar_kernel(
        const float* __restrict__ x, const float* __restrict__ u,
        const float* __restrict__ constk, const float* __restrict__ mask,
        float* __restrict__ psum, float* __restrict__ xpart) {
    const int b  = blockIdx.x;
    const int kt = blockIdx.y;
    __shared__ __align__(16) float ul[NH * H];
    __shared__ float ck[NH];
    __shared__ float wsum[4][NH];
    __shared__ __align__(16) float el[32][NH];
    const int tid = threadIdx.x;
    {
        const float4* ug = (const float4*)(u + (size_t)b * NH * H);
        float4* ul4 = (float4*)ul;
        for (int e = tid; e < NH * H / 4; e += 256) ul4[e] = ug[e];
        if (tid < NH) ck[tid] = constk[b * NH + tid];
    }
    __syncthreads();

    const int jj = tid & 15, kk = tid >> 4;
    const int k0 = kt * 32 + kk * 2;
    float4 xv0[12], xv1[12];
    {
        const float4* xr0 = (const float4*)(x + ((size_t)b * S + k0) * H);
        const float4* xr1 = (const float4*)(x + ((size_t)b * S + k0 + 1) * H);
#pragma unroll
        for (int t = 0; t < 12; ++t) { xv0[t] = xr0[jj + 16 * t]; xv1[t] = xr1[jj + 16 * t]; }
    }
    const float4* ul4 = (const float4*)ul;
    float acc0[NH], acc1[NH];
#pragma unroll
    for (int h = 0; h < NH; ++h) {
        float a0 = 0.f, a1 = 0.f;
#pragma unroll
        for (int t = 0; t < 12; ++t) {
            const float4 uv = ul4[h * 192 + jj + 16 * t];
            a0 += xv0[t].x * uv.x + xv0[t].y * uv.y + xv0[t].z * uv.z + xv0[t].w * uv.w;
            a1 += xv1[t].x * uv.x + xv1[t].y * uv.y + xv1[t].z * uv.z + xv1[t].w * uv.w;
        }
        acc0[h] = a0; acc1[h] = a1;
    }
#pragma unroll
    for (int h = 0; h < NH; ++h) {
#pragma unroll
        for (int d = 1; d < 16; d <<= 1) {
            acc0[h] += __shfl_xor(acc0[h], d);
            acc1[h] += __shfl_xor(acc1[h], d);
        }
    }
    const float mk0 = mask[b * S + k0];
    const float mk1 = mask[b * S + k0 + 1];
    float e0[NH], e1[NH], ps[NH];
#pragma unroll
    for (int h = 0; h < NH; ++h) {
        e0[h] = expf(acc0[h] * 0.125f + ck[h] + mk0);
        e1[h] = expf(acc1[h] * 0.125f + ck[h] + mk1);
        ps[h] = e0[h] + e1[h];
    }
    if (jj == 0) {
#pragma unroll
        for (int h = 0; h < NH; ++h) {
            el[kk * 2 + 0][h] = e0[h];
            el[kk * 2 + 1][h] = e1[h];
        }
    }
#pragma unroll
    for (int h = 0; h < NH; ++h) {
        ps[h] += __shfl_xor(ps[h], 16);
        ps[h] += __shfl_xor(ps[h], 32);
    }
    const int wid = tid >> 6;
    if ((tid & 63) == 0) {
#pragma unroll
        for (int h = 0; h < NH; ++h) wsum[wid][h] = ps[h];
    }
    __syncthreads();   // publishes el[][] AND wsum[][]
    if (tid < NH)
        psum[((size_t)(b * XSPL + kt)) * NH + tid] =
            wsum[0][tid] + wsum[1][tid] + wsum[2][tid] + wsum[3][tid];

    // phase 2: xbar partials; x rows L1/L2-hot (just read above)
    float accx[3][NH];
#pragma unroll
    for (int c = 0; c < 3; ++c)
#pragma unroll
        for (int h = 0; h < NH; ++h) accx[c][h] = 0.f;
    const float* xb = x + ((size_t)b * S + (size_t)kt * 32) * H;
#pragma unroll 4
    for (int k = 0; k < 32; ++k) {
        const float xs0 = xb[(size_t)k * H + tid];
        const float xs1 = xb[(size_t)k * H + tid + 256];
        const float xs2 = xb[(size_t)k * H + tid + 512];
        const float4 ea = *(const float4*)(&el[k][0]);
        const float4 eb = *(const float4*)(&el[k][4]);
        const float4 ec = *(const float4*)(&el[k][8]);
        const float eh[12] = {ea.x, ea.y, ea.z, ea.w,
                              eb.x, eb.y, eb.z, eb.w,
                              ec.x, ec.y, ec.z, ec.w};
#pragma unroll
        for (int h = 0; h < NH; ++h) {
            accx[0][h] += eh[h] * xs0;
            accx[1][h] += eh[h] * xs1;
            accx[2][h] += eh[h] * xs2;
        }
    }
    float* op = xpart + ((size_t)(b * XSPL + kt)) * NH * H + tid;
#pragma unroll
    for (int h = 0; h < NH; ++h) {
        op[(size_t)h * H +   0] = accx[0][h];
        op[(size_t)h * H + 256] = accx[1][h];
        op[(size_t)h * H + 512] = accx[2][h];
    }
}

// out[b,:] = LayerNorm( sum_sp part + bias + resid ) * g + beta
template <int ISPL>
__global__ __launch_bounds__(768) void ln_kernel(
        const float* __restrict__ part, const float* __restrict__ bias,
        const float* __restrict__ resid, int residStride,
        const float* __restrict__ g, const float* __restrict__ bet,
        float* __restrict__ out) {
    __shared__ float red[12];
    const int b = blockIdx.x, j = threadIdx.x;
    float v = bias[j] + resid[(size_t)b * residStride + j];
#pragma unroll
    for (int sp = 0; sp < ISPL; ++sp) v += part[((size_t)sp * B + b) * H + j];
    const float mu = blockReduceSum768(v, red) * (1.0f / H);
    const float d  = v - mu;
    const float var = blockReduceSum768(d * d, red) * (1.0f / H);
    out[(size_t)b * H + j] = d * rsqrtf(var + EPS) * g[j] + bet[j];
}

// pooled = tanh(sum_sp part + bp); cls[b] = pooled . wm + bm
template <int ISPL>
__global__ __launch_bounds__(768) void cls_kernel(
        const float* __restrict__ part, const float* __restrict__ bp,
        const float* __restrict__ wm, const float* __restrict__ bm,
        float* __restrict__ out) {
    __shared__ float red[12];
    const int b = blockIdx.x, j = threadIdx.x;
    float v = bp[j];
#pragma unroll
    for (int sp = 0; sp < ISPL; ++sp) v += part[((size_t)sp * B + b) * H + j];
    v = tanhf(v);
    const float s = blockReduceSum768(v * wm[j], red);
    if (j == 0) out[b] = s + bm[0];
}

} // namespace

extern "C" void kernel_launch(void* const* d_in, const int* in_sizes, int n_in,
                              void* d_out, int out_size, void* d_ws, size_t ws_size,
                              hipStream_t stream) {
    const float* x    = (const float*)d_in[0];
    const float* mask = (const float*)d_in[1];
    const float* wq   = (const float*)d_in[2];
    const float* bq   = (const float*)d_in[3];
    const float* wk   = (const float*)d_in[4];
    const float* bk   = (const float*)d_in[5];
    const float* wv   = (const float*)d_in[6];
    const float* bv   = (const float*)d_in[7];
    const float* wo   = (const float*)d_in[8];
    const float* bo   = (const float*)d_in[9];
    const float* ln1g = (const float*)d_in[10];
    const float* ln1b = (const float*)d_in[11];
    const float* w1   = (const float*)d_in[12];
    const float* b1   = (const float*)d_in[13];
    const float* w2   = (const float*)d_in[14];
    const float* b2   = (const float*)d_in[15];
    const float* ln2g = (const float*)d_in[16];
    const float* ln2b = (const float*)d_in[17];
    const float* wp   = (const float*)d_in[18];
    const float* bp   = (const float*)d_in[19];
    const float* wm   = (const float*)d_in[20];
    const float* bm   = (const float*)d_in[21];
    float* out = (float*)d_out;

    // -------- workspace (lifetime-overlapped arena; ~22 MB) --------
    float* ws = (float*)d_ws;
    size_t o = 0;
    float* u        = ws + o; o += (size_t)B * NH * H;      // 147456
    float* constk   = ws + o; o += 256;
    float* psum     = ws + o; o += (size_t)B * XSPL * NH;   // 6144
    float* attn_out = ws + o; o += (size_t)B * H;
    float* hidden   = ws + o; o += (size_t)B * H;
    float* q0r      = ws + o; o += (size_t)B * H;           // reduced q0 (+bq)
    float* ctxr     = ws + o; o += (size_t)B * H;           // reduced ctx (+bv)
    float* ffn1g    = ws + o; o += (size_t)B * FF;          // reduced+gelu ffn1 (+b1)
    float* arena    = ws + o;
    // arena aliases (sequential lifetimes):
    float* q0_part   = arena;                                  // 24*B*H, dies after q0r
    float* xpart     = arena;                                  // XSPL*B*NH*H = 4718592
    float* ctx_part  = arena + (size_t)XSPL * B * NH * H;      // 24*B*H (reads xpart)
    float* wo_part   = ctx_part + (size_t)24 * B * H;          // 24*B*H
    float* ffn1_part = arena;                                  // 24*B*FF (xpart dead)
    float* ffn2_part = arena + (size_t)24 * B * FF;            // 48*B*H
    float* pool_part = arena;                                  // 24*B*H (ffn1 dead)
    (void)ws_size; (void)in_sizes; (void)n_in; (void)out_size;

    // 1) q0 partials = x[:,0,:] @ wq  (weights read once)
    gemm_partial<H, 24, H><<<dim3(12, 24), 256, 0, stream>>>(x, S * H, 0, wq, q0_part);
    // 2) q0r = bq + sum(q0_part)
    reduce_bias<H, 24, false><<<48, 256, 0, stream>>>(q0_part, bq, q0r);
    // 3) u = wk_head @ q0_head (weights once, all 16 b per block); constk = bk.q0
    u_kernel2<<<dim3(NH, 12), 256, 0, stream>>>(q0r, wk, bk, u, constk);
    // 4) score + xbar fused (x read once from HBM; phase-2 re-read is cache-hot)
    score_xbar_kernel<<<dim3(B, S / 32), 256, 0, stream>>>(x, u, constk, mask, psum, xpart);
    // 5) ctx partials: per-head xbar slice @ wv (fused 32-way reduce + rinv)
    gemm_xpart<24><<<dim3(12, 24), 256, 0, stream>>>(xpart, psum, wv, ctx_part);
    // 6) ctxr = bv + sum(ctx_part);  wo GEMM reads compact ctxr
    reduce_bias<H, 24, false><<<48, 256, 0, stream>>>(ctx_part, bv, ctxr);
    gemm_partial<H, 24, H><<<dim3(12, 24), 256, 0, stream>>>(ctxr, H, 0, wo, wo_part);
    ln_kernel<24><<<B, 768, 0, stream>>>(wo_part, bo, x, S * H, ln1g, ln1b, attn_out);
    // 7) FFN1; global reduce+GELU; FFN2 reads compact gelu'd activations
    gemm_partial<H, 24, FF><<<dim3(48, 24), 256, 0, stream>>>(attn_out, H, 0, w1, ffn1_part);
    reduce_bias<FF, 24, true><<<192, 256, 0, stream>>>(ffn1_part, b1, ffn1g);
    gemm_partial<FF, 48, H><<<dim3(12, 48), 256, 0, stream>>>(ffn1g, FF, 0, w2, ffn2_part);
    ln_kernel<48><<<B, 768, 0, stream>>>(ffn2_part, b2, attn_out, H, ln2g, ln2b, hidden);
    // 8) pooler + classifier
    gemm_partial<H, 24, H><<<dim3(12, 24), 256, 0, stream>>>(hidden, H, 0, wp, pool_part);
    cls_kernel<24><<<B, 768, 0, stream>>>(pool_part, bp, wm, bm, out);
}